// Round 7
// baseline (318.881 us; speedup 1.0000x reference)
//
#include <hip/hip_runtime.h>
#include <hip/hip_bf16.h>

#define EMB 256

typedef __bf16 bf16_t;
typedef __attribute__((ext_vector_type(8))) __bf16 bf16x8;
typedef __attribute__((ext_vector_type(4))) __bf16 bf16x4;
typedef __attribute__((ext_vector_type(4))) float floatx4;

// ---------- helpers ----------
__device__ __forceinline__ int eidx(const int* __restrict__ p, int is64, long long k){
  return is64 ? p[2*k] : p[(int)k];
}
// async global->LDS, 16B per lane; LDS base must be WAVE-UNIFORM, lands at base + lane*16
__device__ __forceinline__ void async_load16(const void* g, void* l){
  __builtin_amdgcn_global_load_lds(
      (const __attribute__((address_space(1))) unsigned int*)g,
      (__attribute__((address_space(3))) unsigned int*)l,
      16, 0, 0);
}
__device__ __forceinline__ float4 cvt4(bf16x4 v){
  return make_float4((float)v.x, (float)v.y, (float)v.z, (float)v.w);
}
// inline dtype detect: int64 edge_index -> high words of first entries are 0
__device__ __forceinline__ int detect64(const int* __restrict__ ei){
  return ((ei[1] | ei[3] | ei[5] | ei[7]) == 0) ? 1 : 0;
}

// ---------- x -> bf16 ----------
__global__ void cvt_x_kernel(const float* __restrict__ x, bf16_t* __restrict__ xb, int n4){
  int t = blockIdx.x*blockDim.x + threadIdx.x;
  if (t >= n4) return;
  const float4 v = *(const float4*)(x + (size_t)t*4);
  bf16x4 o = { (bf16_t)v.x, (bf16_t)v.y, (bf16_t)v.z, (bf16_t)v.w };
  *(bf16x4*)(xb + (size_t)t*4) = o;
}

// ---------- fold W1 into Wkqv; emit TRANSPOSED bf16 WcombT[768][256] + fp32 bcomb[768] ----------
// Output column layout (KV-PACKED): cols [0,256) = q (h*128+d);
// cols [256,768): r = n-256, h = r>>8, g = (r&255)>>3, half = (r>>2)&1, dd = r&3, d = g*4+dd;
//   half 0 -> k_scaled[h][d], half 1 -> v[h][d].
__global__ void prep_weights(const float* __restrict__ Wkqv, const float* __restrict__ bkqv,
                             const float* __restrict__ W1,
                             bf16_t* __restrict__ WcombT, float* __restrict__ bcomb){
  int n = blockIdx.x * blockDim.x + threadIdx.x;   // 0..767 (output col, permuted layout)
  int c = blockIdx.y;                              // 0..256 (k index; 256 = bias)
  if (n >= 768) return;
  const float rs = rsqrtf(128.0f);
  bool isBias = (c == 256);
  const float* arow = isBias ? bkqv : (Wkqv + (size_t)c*768);
  float val;
  if (n < 256){                       // q
    int h = n >> 7, d = n & 127;
    float s = 0.f;
    for (int t = 0; t < 128; ++t)
      s = fmaf(arow[h*128 + t], W1[(size_t)(128 + t)*128 + d], s);
    val = s;
  } else {
    int r = n - 256;
    int h = r >> 8, t8 = r & 255;
    int g = t8 >> 3, half = (t8 >> 2) & 1, dd = t8 & 3;
    int d = g*4 + dd;
    if (half == 0){                   // k (scaled)
      float s = 0.f;
      for (int t = 0; t < 128; ++t)
        s = fmaf(arow[256 + h*128 + t], W1[(size_t)t*128 + d], s);
      val = s * rs;
    } else {                          // v passthrough
      val = arow[512 + h*128 + d];
    }
  }
  if (isBias) bcomb[n] = val;
  else        WcombT[(size_t)n*256 + c] = (bf16_t)val;
}

// ---------- Wout -> transposed bf16 WoutT[256][256] ----------
__global__ void prep_wout(const float* __restrict__ W, bf16_t* __restrict__ Wt){
  int t = blockIdx.x*blockDim.x + threadIdx.x;  // 65536
  int n = t & 255, c = t >> 8;
  Wt[(size_t)n*256 + c] = (bf16_t)W[(size_t)c*256 + n];
}

// ---------- degree count over the 2*E0 non-self edges (dst side) ----------
__global__ void deg_kernel(const int* __restrict__ ei,
                           int* __restrict__ deg, int E0, int Nn){
  int t = blockIdx.x*blockDim.x + threadIdx.x;
  if (t >= 2*E0) return;
  int is64 = detect64(ei);
  int i = (t < E0) ? eidx(ei,is64,(long long)E0+t) : eidx(ei,is64,t-E0);
  i = min(max(i,0), Nn-1);
  atomicAdd(deg + i, 1);
}

// ---------- hierarchical exclusive scan of (deg+1) -> off[0..N] ----------
__global__ __launch_bounds__(1024) void scan1_kernel(const int* __restrict__ deg,
                                                     int* __restrict__ off,
                                                     int* __restrict__ bsum, int N){
  __shared__ int wsum[16];
  int tid = threadIdx.x, lane = tid & 63, w = tid >> 6;
  int i = blockIdx.x*1024 + tid;
  int v = (i < N) ? (deg[i] + 1) : 0;
  int incl = v;
  #pragma unroll
  for (int o = 1; o < 64; o <<= 1){
    int t = __shfl_up(incl, o, 64);
    if (lane >= o) incl += t;
  }
  if (lane == 63) wsum[w] = incl;
  __syncthreads();
  if (w == 0 && lane < 16){
    int sv = wsum[lane];
    #pragma unroll
    for (int o = 1; o < 16; o <<= 1){
      int t = __shfl_up(sv, o, 64);
      if (lane >= o) sv += t;
    }
    wsum[lane] = sv;
  }
  __syncthreads();
  int wpref = (w == 0) ? 0 : wsum[w-1];
  if (i < N) off[i] = wpref + incl - v;          // block-local exclusive
  if (tid == 1023) bsum[blockIdx.x] = wpref + incl;  // block total
}

__global__ __launch_bounds__(1024) void scan2_kernel(int* __restrict__ bsum,
                                                     int* __restrict__ off, int nb, int N){
  __shared__ int wsum[16];
  int tid = threadIdx.x, lane = tid & 63, w = tid >> 6;
  int v = (tid < nb) ? bsum[tid] : 0;
  int incl = v;
  #pragma unroll
  for (int o = 1; o < 64; o <<= 1){
    int t = __shfl_up(incl, o, 64);
    if (lane >= o) incl += t;
  }
  if (lane == 63) wsum[w] = incl;
  __syncthreads();
  if (w == 0 && lane < 16){
    int sv = wsum[lane];
    #pragma unroll
    for (int o = 1; o < 16; o <<= 1){
      int t = __shfl_up(sv, o, 64);
      if (lane >= o) sv += t;
    }
    wsum[lane] = sv;
  }
  __syncthreads();
  int wpref = (w == 0) ? 0 : wsum[w-1];
  if (tid < nb) bsum[tid] = wpref + incl - v;    // exclusive block offsets
  if (tid == 1023) off[N] = wpref + incl;        // grand total
}

__global__ void scan3_kernel(int* __restrict__ off, const int* __restrict__ bsum, int N){
  int i = blockIdx.x*256 + threadIdx.x;
  if (i < N) off[i] += bsum[i >> 10];
}

// ---------- scatter source index j into CSR buckets (incl. self-loops) ----------
__global__ void scatter_kernel(const int* __restrict__ ei,
                               const int* __restrict__ off, int* __restrict__ cursor,
                               int* __restrict__ bj, int E0, int Nn){
  int e = blockIdx.x*blockDim.x + threadIdx.x;
  int E = 2*E0 + Nn;
  if (e >= E) return;
  int is64 = detect64(ei);
  int j, i;
  if (e < E0){ j = eidx(ei,is64,e); i = eidx(ei,is64,(long long)E0+e); }
  else if (e < 2*E0){ int t = e - E0; i = eidx(ei,is64,t); j = eidx(ei,is64,(long long)E0+t); }
  else { i = j = e - 2*E0; }
  i = min(max(i,0), Nn-1); j = min(max(j,0), Nn-1);
  int pos = atomicAdd(cursor + i, 1);
  bj[off[i] + pos] = j;
}

// ---------- B-RESIDENT bf16 MFMA GEMM, K=256 (full reduction in LDS) ----------
// THEORY (m233): the per-k-step stage+vmcnt(0)+barrier pair is ~72% of a 2-phase
// loop's critical path; with only 8 k-steps the loop never leaves that regime,
// which is why 6 structural variants all measured 58-64 us. K=256 is the ENTIRE
// reduction, so a 128n x 256k B-panel (64 KB) fits in LDS: load it ONCE (the
// kernel's only barrier), then run a BARRIER-FREE fully-unrolled k-loop with A
// fragments streamed global->register (4x16B/lane/kt; B from low-latency LDS).
// Compiler can pipeline all 32 A-loads against 128 MFMAs with no drain points.
// Block: 512 thr / 8 waves, wave owns 64x64 (acc 4x4); MLOOP m-tiles amortize
// the B-load. MFMA order per output identical to prior rounds (same numerics).
// MODE 0: C(bf16) = AB + bias[n]
// MODE 1: C(fp32) = relu(AB + (deg[m]+1)*bias[n]) + xres[m*N+n]
template<int MODE, int MLOOP, typename OutT>
__global__ __launch_bounds__(512, 4) void mfma_gemmB(
    const bf16_t* __restrict__ A, const bf16_t* __restrict__ Bt,
    const float* __restrict__ bias, OutT* __restrict__ C,
    int M, int N,
    const int* __restrict__ deg, const float* __restrict__ xres)
{
  __shared__ bf16_t Bs[128*256];   // 64 KB B-panel, fragment-major: (fr,kt) 1KB blocks
  const int tid = threadIdx.x;
  const int wave = tid >> 6, lane = tid & 63;       // 8 waves
  const int row16 = lane & 15, quad = lane >> 4;
  const int n0 = blockIdx.y << 7;                   // n-strip of 128

  // stage B-panel once: wave w -> fragments (fr=w, kt=0..7)
  {
    const bf16_t* gsrc = Bt + (size_t)(n0 + wave*16 + row16)*256 + quad*8;
    char* ldst = (char*)Bs + wave*8192;
    #pragma unroll
    for (int kt = 0; kt < 8; ++kt)
      async_load16(gsrc + kt*32, ldst + kt*1024);
  }
  __syncthreads();   // the ONLY barrier in this kernel

  const int wm = (wave >> 1) * 64;    // 0,64,128,192
  const int wn = (wave & 1) * 64;     // 0,64

  float4 b4[4];
  #pragma unroll
  for (int nt=0;nt<4;++nt)
    b4[nt] = *(const float4*)(bias + n0 + wn + nt*16 + quad*4);

  for (int l = 0; l < MLOOP; ++l){
    const int m0 = (blockIdx.x*MLOOP + l) << 8;
    if (m0 >= M) return;

    // A fragment row pointers (rows clamped for the tail tile)
    const bf16_t* ap[4];
    #pragma unroll
    for (int t = 0; t < 4; ++t)
      ap[t] = A + (size_t)min(m0 + wm + t*16 + row16, M-1)*256 + quad*8;

    floatx4 acc[4][4];
    #pragma unroll
    for (int a=0;a<4;++a)
      #pragma unroll
      for (int b=0;b<4;++b) acc[a][b] = (floatx4){0.f,0.f,0.f,0.f};

    // barrier-free k-loop: A global->reg, B LDS-resident
    #pragma unroll
    for (int kt = 0; kt < 8; ++kt){
      bf16x8 af[4], bfr[4];
      #pragma unroll
      for (int t = 0; t < 4; ++t)
        af[t]  = *(const bf16x8*)(ap[t] + kt*32);
      #pragma unroll
      for (int t = 0; t < 4; ++t)
        bfr[t] = *(const bf16x8*)((const char*)Bs + (((wn>>4)+t)*8 + kt)*1024 + lane*16);
      // SWAPPED operands: D tile gets row=n_local, col=m_local
      #pragma unroll
      for (int mt=0;mt<4;++mt)
        #pragma unroll
        for (int nt=0;nt<4;++nt)
          acc[mt][nt] = __builtin_amdgcn_mfma_f32_16x16x32_bf16(bfr[nt], af[mt], acc[mt][nt], 0,0,0);
    }

    // epilogue: lane holds m = lane&15, n = quad*4 + {0..3} per tile -> vector stores
    #pragma unroll
    for (int mt=0;mt<4;++mt){
      const int m = m0 + wm + mt*16 + row16;
      if (m >= M) continue;
      const float dg = (MODE==1) ? (float)(deg[m]+1) : 0.f;
      #pragma unroll
      for (int nt=0;nt<4;++nt){
        const int nb = n0 + wn + nt*16 + quad*4;
        if (MODE == 0){
          bf16x4 o = { (bf16_t)(acc[mt][nt][0] + b4[nt].x),
                       (bf16_t)(acc[mt][nt][1] + b4[nt].y),
                       (bf16_t)(acc[mt][nt][2] + b4[nt].z),
                       (bf16_t)(acc[mt][nt][3] + b4[nt].w) };
          *(bf16x4*)((bf16_t*)C + (size_t)m*N + nb) = o;
        } else {
          const float4 xr = *(const float4*)(xres + (size_t)m*N + nb);
          float4 o;
          o.x = fmaxf(acc[mt][nt][0] + dg*b4[nt].x, 0.f) + xr.x;
          o.y = fmaxf(acc[mt][nt][1] + dg*b4[nt].y, 0.f) + xr.y;
          o.z = fmaxf(acc[mt][nt][2] + dg*b4[nt].z, 0.f) + xr.z;
          o.w = fmaxf(acc[mt][nt][3] + dg*b4[nt].w, 0.f) + xr.w;
          *(float4*)((float*)C + (size_t)m*N + nb) = o;
        }
      }
    }
  }
}

// ---------- fused attention: score + online softmax + aggregate, one wave per node ----------
// P layout: [0,256) q; [256,768) kv-packed. BATCHED x4 (see round-4 notes).
__device__ __forceinline__ float score4(bf16x8 kvv, float4 qv, float4 b1v, float4 w2v){
  return fmaxf(qv.x+(float)kvv[0]+b1v.x, 0.f)*w2v.x
       + fmaxf(qv.y+(float)kvv[1]+b1v.y, 0.f)*w2v.y
       + fmaxf(qv.z+(float)kvv[2]+b1v.z, 0.f)*w2v.z
       + fmaxf(qv.w+(float)kvv[3]+b1v.w, 0.f)*w2v.w;
}
__device__ __forceinline__ float hredux(float p){
  #pragma unroll
  for (int o = 16; o >= 1; o >>= 1)
    p += __shfl_xor(p, o, 64);
  return p;
}
__global__ __launch_bounds__(256) void fused_attn_kernel(
    const bf16_t* __restrict__ P, const int* __restrict__ bj, const int* __restrict__ off,
    const float* __restrict__ b1, const float* __restrict__ W2, const float* __restrict__ b2,
    bf16_t* __restrict__ aggb, int Nn)
{
  int i = blockIdx.x * (blockDim.x >> 6) + (threadIdx.x >> 6);
  if (i >= Nn) return;
  int lane = threadIdx.x & 63;
  int h = lane >> 5, g = lane & 31, d = g * 4;

  const float4 qv  = cvt4(*(const bf16x4*)(P + (size_t)i*768 + h*128 + d));
  const float4 b1v = *(const float4*)(b1 + d);
  const float4 w2v = *(const float4*)(W2 + d);
  const float b2v  = b2[0];
  const bf16_t* __restrict__ Pkv = P + 256 + h*256 + g*8;

  float m = -3.0e38f, s = 0.f;
  float4 acc = make_float4(0.f,0.f,0.f,0.f);
  const int s0 = off[i], s1 = off[i+1], s1m1 = s1 - 1;

  for (int t = s0; t < s1; t += 4){
    const int cnt = s1 - t;                 // >= 1
    const int jA = bj[t];
    const int jB = bj[min(t+1, s1m1)];
    const int jC = bj[min(t+2, s1m1)];
    const int jD = bj[min(t+3, s1m1)];
    const bf16x8 kA = *(const bf16x8*)(Pkv + (size_t)jA*768);
    const bf16x8 kB = *(const bf16x8*)(Pkv + (size_t)jB*768);
    const bf16x8 kC = *(const bf16x8*)(Pkv + (size_t)jC*768);
    const bf16x8 kD = *(const bf16x8*)(Pkv + (size_t)jD*768);
    float pA = hredux(score4(kA, qv, b1v, w2v));
    float pB = hredux(score4(kB, qv, b1v, w2v));
    float pC = hredux(score4(kC, qv, b1v, w2v));
    float pD = hredux(score4(kD, qv, b1v, w2v));
    const float aA = pA + b2v;
    const float aB = (cnt > 1) ? pB + b2v : -3.0e38f;
    const float aC = (cnt > 2) ? pC + b2v : -3.0e38f;
    const float aD = (cnt > 3) ? pD + b2v : -3.0e38f;
    const float amax = fmaxf(fmaxf(aA, aB), fmaxf(aC, aD));
    const float mn = fmaxf(m, amax);
    const float sc = __expf(m - mn);
    const float eA = __expf(aA - mn);       // masked lanes -> exp(-inf) = 0
    const float eB = __expf(aB - mn);
    const float eC = __expf(aC - mn);
    const float eD = __expf(aD - mn);
    s = s*sc + ((eA + eB) + (eC + eD));
    acc.x = acc.x*sc + ((eA*(float)kA[4] + eB*(float)kB[4]) + (eC*(float)kC[4] + eD*(float)kD[4]));
    acc.y = acc.y*sc + ((eA*(float)kA[5] + eB*(float)kB[5]) + (eC*(float)kC[5] + eD*(float)kD[5]));
    acc.z = acc.z*sc + ((eA*(float)kA[6] + eB*(float)kB[6]) + (eC*(float)kC[6] + eD*(float)kD[6]));
    acc.w = acc.w*sc + ((eA*(float)kA[7] + eB*(float)kB[7]) + (eC*(float)kC[7] + eD*(float)kD[7]));
    m = mn;
  }
  float inv = 1.f / (s + 1e-16f);
  bf16x4 ob = { (bf16_t)(acc.x*inv), (bf16_t)(acc.y*inv), (bf16_t)(acc.z*inv), (bf16_t)(acc.w*inv) };
  *(bf16x4*)(aggb + (size_t)i*256 + h*128 + d) = ob;
}

// ---------- launch ----------
extern "C" void kernel_launch(void* const* d_in, const int* in_sizes, int n_in,
                              void* d_out, int out_size, void* d_ws, size_t ws_size,
                              hipStream_t stream)
{
  const float* x     = (const float*)d_in[0];
  const int*   ei    = (const int*)d_in[1];
  const float* Wkqv  = (const float*)d_in[2];
  const float* bkqv  = (const float*)d_in[3];
  const float* W1    = (const float*)d_in[4];
  const float* b1    = (const float*)d_in[5];
  const float* W2    = (const float*)d_in[6];
  const float* b2    = (const float*)d_in[7];
  const float* Wout  = (const float*)d_in[8];
  const float* bout  = (const float*)d_in[9];
  float* out = (float*)d_out;

  const int N  = in_sizes[0] / EMB;   // 50000
  const int E0 = in_sizes[1] / 2;     // 100000
  const int E  = 2*E0 + N;            // 250000

  // workspace layout (fp32-word offsets; all 16B-aligned)
  float* base = (float*)d_ws;
  bf16_t* WcombT = (bf16_t*)base;                       // 768*256 bf16
  float*  bcomb  = base + 98304;                        // 768 w
  bf16_t* WoutT  = (bf16_t*)(base + 98304 + 768);       // 256*256 bf16
  bf16_t* xb     = (bf16_t*)(base + 131840);            // N*256 bf16
  bf16_t* Pb     = (bf16_t*)(base + 131840 + 6400000);  // N*768 bf16
  bf16_t* aggb   = (bf16_t*)(Pb + (size_t)N*768);       // N*256 bf16
  int* deg       = (int*)(aggb + (size_t)N*256);        // N
  int* cursor    = deg + N;                             // N
  int* flag      = cursor + N;                          // 1 (unused)
  int* off       = flag + 1;                            // N+1
  int* bj        = off + (N+1);                         // E
  // scratch for scan block sums: reuse aggb region (written only later by attn)
  int* bsum      = (int*)aggb;                          // <=1024 ints

  hipMemsetAsync(deg, 0, (size_t)2*N*sizeof(int), stream);  // deg + cursor

  cvt_x_kernel<<<((N*EMB/4)+255)/256,256,0,stream>>>(x, xb, N*EMB/4);
  prep_weights<<<dim3(3,257),256,0,stream>>>(Wkqv, bkqv, W1, WcombT, bcomb);
  prep_wout<<<256,256,0,stream>>>(Wout, WoutT);

  deg_kernel<<<(2*E0+255)/256,256,0,stream>>>(ei, deg, E0, N);
  const int nb = (N + 1023)/1024;
  scan1_kernel<<<nb,1024,0,stream>>>(deg, off, bsum, N);
  scan2_kernel<<<1,1024,0,stream>>>(bsum, off, nb, N);
  scan3_kernel<<<(N+255)/256,256,0,stream>>>(off, bsum, N);
  scatter_kernel<<<(E+255)/256,256,0,stream>>>(ei, off, cursor, bj, E0, N);

  const int nmt = (N + 255)/256;      // 196 m-tiles of 256 rows
  // gemm<0>: 6 n-strips of 128 (N=768), 3 m-tiles per block -> 66x6 = 396 blocks
  mfma_gemmB<0, 3, bf16_t><<<dim3((nmt+2)/3, 6),512,0,stream>>>(
      xb, WcombT, bcomb, Pb, N, 768, nullptr, nullptr);
  fused_attn_kernel<<<(N+3)/4,256,0,stream>>>(Pb, bj, off, b1, W2, b2, aggb, N);
  // gemm<1>: 2 n-strips of 128 (N=256), 1 m-tile per block -> 196x2 = 392 blocks
  mfma_gemmB<1, 1, float><<<dim3(nmt, 2),512,0,stream>>>(
      aggb, WoutT, bout, out, N, 256, deg, x);
}

// Round 8
// 314.397 us; speedup vs baseline: 1.0143x; 1.0143x over previous
//
#include <hip/hip_runtime.h>
#include <hip/hip_bf16.h>

#define EMB 256

typedef __bf16 bf16_t;
typedef __attribute__((ext_vector_type(8))) __bf16 bf16x8;
typedef __attribute__((ext_vector_type(4))) __bf16 bf16x4;
typedef __attribute__((ext_vector_type(4))) float floatx4;

// ---------- helpers ----------
__device__ __forceinline__ int eidx(const int* __restrict__ p, int is64, long long k){
  return is64 ? p[2*k] : p[(int)k];
}
// async global->LDS, 16B per lane; LDS base must be WAVE-UNIFORM, lands at base + lane*16
__device__ __forceinline__ void async_load16(const void* g, void* l){
  __builtin_amdgcn_global_load_lds(
      (const __attribute__((address_space(1))) unsigned int*)g,
      (__attribute__((address_space(3))) unsigned int*)l,
      16, 0, 0);
}
__device__ __forceinline__ float4 cvt4(bf16x4 v){
  return make_float4((float)v.x, (float)v.y, (float)v.z, (float)v.w);
}
// inline dtype detect: int64 edge_index -> high words of first entries are 0
__device__ __forceinline__ int detect64(const int* __restrict__ ei){
  return ((ei[1] | ei[3] | ei[5] | ei[7]) == 0) ? 1 : 0;
}

// ---------- x -> bf16 ----------
__global__ void cvt_x_kernel(const float* __restrict__ x, bf16_t* __restrict__ xb, int n4){
  int t = blockIdx.x*blockDim.x + threadIdx.x;
  if (t >= n4) return;
  const float4 v = *(const float4*)(x + (size_t)t*4);
  bf16x4 o = { (bf16_t)v.x, (bf16_t)v.y, (bf16_t)v.z, (bf16_t)v.w };
  *(bf16x4*)(xb + (size_t)t*4) = o;
}

// ---------- fold W1 into Wkqv; emit TRANSPOSED bf16 WcombT[768][256] + fp32 bcomb[768] ----------
// Output column layout (KV-PACKED): cols [0,256) = q (h*128+d);
// cols [256,768): r = n-256, h = r>>8, g = (r&255)>>3, half = (r>>2)&1, dd = r&3, d = g*4+dd;
//   half 0 -> k_scaled[h][d], half 1 -> v[h][d].
__global__ void prep_weights(const float* __restrict__ Wkqv, const float* __restrict__ bkqv,
                             const float* __restrict__ W1,
                             bf16_t* __restrict__ WcombT, float* __restrict__ bcomb){
  int n = blockIdx.x * blockDim.x + threadIdx.x;   // 0..767 (output col, permuted layout)
  int c = blockIdx.y;                              // 0..256 (k index; 256 = bias)
  if (n >= 768) return;
  const float rs = rsqrtf(128.0f);
  bool isBias = (c == 256);
  const float* arow = isBias ? bkqv : (Wkqv + (size_t)c*768);
  float val;
  if (n < 256){                       // q
    int h = n >> 7, d = n & 127;
    float s = 0.f;
    for (int t = 0; t < 128; ++t)
      s = fmaf(arow[h*128 + t], W1[(size_t)(128 + t)*128 + d], s);
    val = s;
  } else {
    int r = n - 256;
    int h = r >> 8, t8 = r & 255;
    int g = t8 >> 3, half = (t8 >> 2) & 1, dd = t8 & 3;
    int d = g*4 + dd;
    if (half == 0){                   // k (scaled)
      float s = 0.f;
      for (int t = 0; t < 128; ++t)
        s = fmaf(arow[256 + h*128 + t], W1[(size_t)t*128 + d], s);
      val = s * rs;
    } else {                          // v passthrough
      val = arow[512 + h*128 + d];
    }
  }
  if (isBias) bcomb[n] = val;
  else        WcombT[(size_t)n*256 + c] = (bf16_t)val;
}

// ---------- Wout -> transposed bf16 WoutT[256][256] ----------
__global__ void prep_wout(const float* __restrict__ W, bf16_t* __restrict__ Wt){
  int t = blockIdx.x*blockDim.x + threadIdx.x;  // 65536
  int n = t & 255, c = t >> 8;
  Wt[(size_t)n*256 + c] = (bf16_t)W[(size_t)c*256 + n];
}

// ---------- degree count over the 2*E0 non-self edges (dst side) ----------
__global__ void deg_kernel(const int* __restrict__ ei,
                           int* __restrict__ deg, int E0, int Nn){
  int t = blockIdx.x*blockDim.x + threadIdx.x;
  if (t >= 2*E0) return;
  int is64 = detect64(ei);
  int i = (t < E0) ? eidx(ei,is64,(long long)E0+t) : eidx(ei,is64,t-E0);
  i = min(max(i,0), Nn-1);
  atomicAdd(deg + i, 1);
}

// ---------- hierarchical exclusive scan of (deg+1) -> off[0..N] ----------
__global__ __launch_bounds__(1024) void scan1_kernel(const int* __restrict__ deg,
                                                     int* __restrict__ off,
                                                     int* __restrict__ bsum, int N){
  __shared__ int wsum[16];
  int tid = threadIdx.x, lane = tid & 63, w = tid >> 6;
  int i = blockIdx.x*1024 + tid;
  int v = (i < N) ? (deg[i] + 1) : 0;
  int incl = v;
  #pragma unroll
  for (int o = 1; o < 64; o <<= 1){
    int t = __shfl_up(incl, o, 64);
    if (lane >= o) incl += t;
  }
  if (lane == 63) wsum[w] = incl;
  __syncthreads();
  if (w == 0 && lane < 16){
    int sv = wsum[lane];
    #pragma unroll
    for (int o = 1; o < 16; o <<= 1){
      int t = __shfl_up(sv, o, 64);
      if (lane >= o) sv += t;
    }
    wsum[lane] = sv;
  }
  __syncthreads();
  int wpref = (w == 0) ? 0 : wsum[w-1];
  if (i < N) off[i] = wpref + incl - v;          // block-local exclusive
  if (tid == 1023) bsum[blockIdx.x] = wpref + incl;  // block total
}

__global__ __launch_bounds__(1024) void scan2_kernel(int* __restrict__ bsum,
                                                     int* __restrict__ off, int nb, int N){
  __shared__ int wsum[16];
  int tid = threadIdx.x, lane = tid & 63, w = tid >> 6;
  int v = (tid < nb) ? bsum[tid] : 0;
  int incl = v;
  #pragma unroll
  for (int o = 1; o < 64; o <<= 1){
    int t = __shfl_up(incl, o, 64);
    if (lane >= o) incl += t;
  }
  if (lane == 63) wsum[w] = incl;
  __syncthreads();
  if (w == 0 && lane < 16){
    int sv = wsum[lane];
    #pragma unroll
    for (int o = 1; o < 16; o <<= 1){
      int t = __shfl_up(sv, o, 64);
      if (lane >= o) sv += t;
    }
    wsum[lane] = sv;
  }
  __syncthreads();
  int wpref = (w == 0) ? 0 : wsum[w-1];
  if (tid < nb) bsum[tid] = wpref + incl - v;    // exclusive block offsets
  if (tid == 1023) off[N] = wpref + incl;        // grand total
}

__global__ void scan3_kernel(int* __restrict__ off, const int* __restrict__ bsum, int N){
  int i = blockIdx.x*256 + threadIdx.x;
  if (i < N) off[i] += bsum[i >> 10];
}

// ---------- scatter source index j into CSR buckets (incl. self-loops) ----------
__global__ void scatter_kernel(const int* __restrict__ ei,
                               const int* __restrict__ off, int* __restrict__ cursor,
                               int* __restrict__ bj, int E0, int Nn){
  int e = blockIdx.x*blockDim.x + threadIdx.x;
  int E = 2*E0 + Nn;
  if (e >= E) return;
  int is64 = detect64(ei);
  int j, i;
  if (e < E0){ j = eidx(ei,is64,e); i = eidx(ei,is64,(long long)E0+e); }
  else if (e < 2*E0){ int t = e - E0; i = eidx(ei,is64,t); j = eidx(ei,is64,(long long)E0+t); }
  else { i = j = e - 2*E0; }
  i = min(max(i,0), Nn-1); j = min(max(j,0), Nn-1);
  int pos = atomicAdd(cursor + i, 1);
  bj[off[i] + pos] = j;
}

// ---------- 256x256-tile bf16 MFMA GEMM (MODE 0), K=256 -- round-6 best, verbatim ----------
__global__ __launch_bounds__(1024, 4) void mfma_gemm256(
    const bf16_t* __restrict__ A, const bf16_t* __restrict__ Bt,
    const float* __restrict__ bias, bf16_t* __restrict__ C,
    int M, int N)
{
  __shared__ bf16_t As[2][256*32];   // 16 KB each
  __shared__ bf16_t Bs[2][256*32];
  const int tid = threadIdx.x;
  const int wave = tid >> 6, lane = tid & 63;   // wave 0..15
  const int row16 = lane & 15, quad = lane >> 4;

  const int nn = N >> 8;               // n-strips of 256
  const int bid = blockIdx.x;
  const int strip = bid / (8*nn);
  const int inner = bid % (8*nn);
  const int m0 = (strip*8 + (inner & 7)) * 256;
  const int n0 = (inner >> 3) * 256;
  const int wm  = (wave >> 2) * 64;    // 0,64,128,192
  const int wnq = (wave & 3) * 64;     // 0,64,128,192

  const int gm0 = min(m0 + wave*16 + row16, M-1);
  const int gn0 = n0 + wave*16 + row16;

  async_load16(A  + (size_t)gm0*256 + quad*8, (char*)As[0] + wave*1024);
  async_load16(Bt + (size_t)gn0*256 + quad*8, (char*)Bs[0] + wave*1024);

  floatx4 acc[4][4];
  #pragma unroll
  for (int a=0;a<4;++a)
    #pragma unroll
    for (int b=0;b<4;++b) acc[a][b] = (floatx4){0.f,0.f,0.f,0.f};

  #pragma unroll
  for (int kt = 0; kt < 8; ++kt){
    const int cur = kt & 1, nxt = cur ^ 1;
    const int k1 = (kt+1)*32;

    __syncthreads();   // buffer[cur] staged; buffer[nxt] free

    if (kt < 7){
      async_load16(A  + (size_t)gm0*256 + k1 + quad*8, (char*)As[nxt] + wave*1024);
      async_load16(Bt + (size_t)gn0*256 + k1 + quad*8, (char*)Bs[nxt] + wave*1024);
    }

    bf16x8 af[4], bfr[4];
    #pragma unroll
    for (int t = 0; t < 4; ++t){
      af[t]  = *(const bf16x8*)((const char*)As[cur] + ((wm>>4)+t)*1024 + lane*16);
      bfr[t] = *(const bf16x8*)((const char*)Bs[cur] + ((wnq>>4)+t)*1024 + lane*16);
    }
    // SWAPPED operands: D tile gets row=n_local, col=m_local
    #pragma unroll
    for (int mt=0;mt<4;++mt)
      #pragma unroll
      for (int nt=0;nt<4;++nt)
        acc[mt][nt] = __builtin_amdgcn_mfma_f32_16x16x32_bf16(bfr[nt], af[mt], acc[mt][nt], 0,0,0);
  }

  // epilogue: lane holds m = lane&15, n = quad*4 + {0..3} per tile -> 8B stores
  float4 b4[4];
  #pragma unroll
  for (int nt=0;nt<4;++nt)
    b4[nt] = *(const float4*)(bias + n0 + wnq + nt*16 + quad*4);

  #pragma unroll
  for (int mt=0;mt<4;++mt){
    const int m = m0 + wm + mt*16 + row16;
    if (m >= M) continue;
    #pragma unroll
    for (int nt=0;nt<4;++nt){
      const int nb = n0 + wnq + nt*16 + quad*4;
      bf16x4 o = { (bf16_t)(acc[mt][nt][0] + b4[nt].x),
                   (bf16_t)(acc[mt][nt][1] + b4[nt].y),
                   (bf16_t)(acc[mt][nt][2] + b4[nt].z),
                   (bf16_t)(acc[mt][nt][3] + b4[nt].w) };
      *(bf16x4*)(C + (size_t)m*N + nb) = o;
    }
  }
}

// ---------- 128m x 256n tile GEMM (MODE 1), K=256, N=256: A/xres/out touched ONCE ----------
// out = relu(AB + (deg[m]+1)*bias[n]) + xres[m*N+n], fp32 out. Same single-barrier
// double-buffered skeleton; 8 waves, wave owns 64x64 (acc 4x4). LDS 48 KB.
__global__ __launch_bounds__(512, 4) void mfma_gemm_m1(
    const bf16_t* __restrict__ A, const bf16_t* __restrict__ Bt,
    const float* __restrict__ bias, float* __restrict__ C,
    int M, int N,
    const int* __restrict__ deg, const float* __restrict__ xres)
{
  __shared__ bf16_t As[2][128*32];   // 8 KB each
  __shared__ bf16_t Bs[2][256*32];   // 16 KB each
  const int tid = threadIdx.x;
  const int wave = tid >> 6, lane = tid & 63;   // wave 0..7
  const int row16 = lane & 15, quad = lane >> 4;

  // XCD swizzle over m-strips (single n-strip)
  const int bid = blockIdx.x;
  const int m0 = ((bid/8)*8 + (bid & 7)) * 128;
  const int wm  = (wave >> 2) * 64;   // 0 or 64
  const int wnq = (wave & 3) * 64;    // 0,64,128,192

  const int gm0 = min(m0 + wave*16 + row16, M-1);
  const int gnA = wave*16 + row16;          // B frag rows: wave and wave+8
  const int gnB = (wave+8)*16 + row16;

  async_load16(A  + (size_t)gm0*256 + quad*8, (char*)As[0] + wave*1024);
  async_load16(Bt + (size_t)gnA*256 + quad*8, (char*)Bs[0] + wave*1024);
  async_load16(Bt + (size_t)gnB*256 + quad*8, (char*)Bs[0] + (wave+8)*1024);

  floatx4 acc[4][4];
  #pragma unroll
  for (int a=0;a<4;++a)
    #pragma unroll
    for (int b=0;b<4;++b) acc[a][b] = (floatx4){0.f,0.f,0.f,0.f};

  #pragma unroll
  for (int kt = 0; kt < 8; ++kt){
    const int cur = kt & 1, nxt = cur ^ 1;
    const int k1 = (kt+1)*32;

    __syncthreads();   // buffer[cur] staged; buffer[nxt] free

    if (kt < 7){
      async_load16(A  + (size_t)gm0*256 + k1 + quad*8, (char*)As[nxt] + wave*1024);
      async_load16(Bt + (size_t)gnA*256 + k1 + quad*8, (char*)Bs[nxt] + wave*1024);
      async_load16(Bt + (size_t)gnB*256 + k1 + quad*8, (char*)Bs[nxt] + (wave+8)*1024);
    }

    bf16x8 af[4], bfr[4];
    #pragma unroll
    for (int t = 0; t < 4; ++t){
      af[t]  = *(const bf16x8*)((const char*)As[cur] + ((wm>>4)+t)*1024 + lane*16);
      bfr[t] = *(const bf16x8*)((const char*)Bs[cur] + ((wnq>>4)+t)*1024 + lane*16);
    }
    #pragma unroll
    for (int mt=0;mt<4;++mt)
      #pragma unroll
      for (int nt=0;nt<4;++nt)
        acc[mt][nt] = __builtin_amdgcn_mfma_f32_16x16x32_bf16(bfr[nt], af[mt], acc[mt][nt], 0,0,0);
  }

  float4 b4[4];
  #pragma unroll
  for (int nt=0;nt<4;++nt)
    b4[nt] = *(const float4*)(bias + wnq + nt*16 + quad*4);

  #pragma unroll
  for (int mt=0;mt<4;++mt){
    const int m = m0 + wm + mt*16 + row16;
    if (m >= M) continue;
    const float dg = (float)(deg[m]+1);
    #pragma unroll
    for (int nt=0;nt<4;++nt){
      const int nb = wnq + nt*16 + quad*4;
      const float4 xr = *(const float4*)(xres + (size_t)m*N + nb);
      float4 o;
      o.x = fmaxf(acc[mt][nt][0] + dg*b4[nt].x, 0.f) + xr.x;
      o.y = fmaxf(acc[mt][nt][1] + dg*b4[nt].y, 0.f) + xr.y;
      o.z = fmaxf(acc[mt][nt][2] + dg*b4[nt].z, 0.f) + xr.z;
      o.w = fmaxf(acc[mt][nt][3] + dg*b4[nt].w, 0.f) + xr.w;
      *(float4*)(C + (size_t)m*N + nb) = o;
    }
  }
}

// ---------- fused attention: score + online softmax + aggregate, one wave per node ----------
__device__ __forceinline__ float score4(bf16x8 kvv, float4 qv, float4 b1v, float4 w2v){
  return fmaxf(qv.x+(float)kvv[0]+b1v.x, 0.f)*w2v.x
       + fmaxf(qv.y+(float)kvv[1]+b1v.y, 0.f)*w2v.y
       + fmaxf(qv.z+(float)kvv[2]+b1v.z, 0.f)*w2v.z
       + fmaxf(qv.w+(float)kvv[3]+b1v.w, 0.f)*w2v.w;
}
__device__ __forceinline__ float hredux(float p){
  #pragma unroll
  for (int o = 16; o >= 1; o >>= 1)
    p += __shfl_xor(p, o, 64);
  return p;
}
__global__ __launch_bounds__(256) void fused_attn_kernel(
    const bf16_t* __restrict__ P, const int* __restrict__ bj, const int* __restrict__ off,
    const float* __restrict__ b1, const float* __restrict__ W2, const float* __restrict__ b2,
    bf16_t* __restrict__ aggb, int Nn)
{
  int i = blockIdx.x * (blockDim.x >> 6) + (threadIdx.x >> 6);
  if (i >= Nn) return;
  int lane = threadIdx.x & 63;
  int h = lane >> 5, g = lane & 31, d = g * 4;

  const float4 qv  = cvt4(*(const bf16x4*)(P + (size_t)i*768 + h*128 + d));
  const float4 b1v = *(const float4*)(b1 + d);
  const float4 w2v = *(const float4*)(W2 + d);
  const float b2v  = b2[0];
  const bf16_t* __restrict__ Pkv = P + 256 + h*256 + g*8;

  float m = -3.0e38f, s = 0.f;
  float4 acc = make_float4(0.f,0.f,0.f,0.f);
  const int s0 = off[i], s1 = off[i+1], s1m1 = s1 - 1;

  for (int t = s0; t < s1; t += 4){
    const int cnt = s1 - t;                 // >= 1
    const int jA = bj[t];
    const int jB = bj[min(t+1, s1m1)];
    const int jC = bj[min(t+2, s1m1)];
    const int jD = bj[min(t+3, s1m1)];
    const bf16x8 kA = *(const bf16x8*)(Pkv + (size_t)jA*768);
    const bf16x8 kB = *(const bf16x8*)(Pkv + (size_t)jB*768);
    const bf16x8 kC = *(const bf16x8*)(Pkv + (size_t)jC*768);
    const bf16x8 kD = *(const bf16x8*)(Pkv + (size_t)jD*768);
    float pA = hredux(score4(kA, qv, b1v, w2v));
    float pB = hredux(score4(kB, qv, b1v, w2v));
    float pC = hredux(score4(kC, qv, b1v, w2v));
    float pD = hredux(score4(kD, qv, b1v, w2v));
    const float aA = pA + b2v;
    const float aB = (cnt > 1) ? pB + b2v : -3.0e38f;
    const float aC = (cnt > 2) ? pC + b2v : -3.0e38f;
    const float aD = (cnt > 3) ? pD + b2v : -3.0e38f;
    const float amax = fmaxf(fmaxf(aA, aB), fmaxf(aC, aD));
    const float mn = fmaxf(m, amax);
    const float sc = __expf(m - mn);
    const float eA = __expf(aA - mn);       // masked lanes -> exp(-inf) = 0
    const float eB = __expf(aB - mn);
    const float eC = __expf(aC - mn);
    const float eD = __expf(aD - mn);
    s = s*sc + ((eA + eB) + (eC + eD));
    acc.x = acc.x*sc + ((eA*(float)kA[4] + eB*(float)kB[4]) + (eC*(float)kC[4] + eD*(float)kD[4]));
    acc.y = acc.y*sc + ((eA*(float)kA[5] + eB*(float)kB[5]) + (eC*(float)kC[5] + eD*(float)kD[5]));
    acc.z = acc.z*sc + ((eA*(float)kA[6] + eB*(float)kB[6]) + (eC*(float)kC[6] + eD*(float)kD[6]));
    acc.w = acc.w*sc + ((eA*(float)kA[7] + eB*(float)kB[7]) + (eC*(float)kC[7] + eD*(float)kD[7]));
    m = mn;
  }
  float inv = 1.f / (s + 1e-16f);
  bf16x4 ob = { (bf16_t)(acc.x*inv), (bf16_t)(acc.y*inv), (bf16_t)(acc.z*inv), (bf16_t)(acc.w*inv) };
  *(bf16x4*)(aggb + (size_t)i*256 + h*128 + d) = ob;
}

// ---------- launch ----------
extern "C" void kernel_launch(void* const* d_in, const int* in_sizes, int n_in,
                              void* d_out, int out_size, void* d_ws, size_t ws_size,
                              hipStream_t stream)
{
  const float* x     = (const float*)d_in[0];
  const int*   ei    = (const int*)d_in[1];
  const float* Wkqv  = (const float*)d_in[2];
  const float* bkqv  = (const float*)d_in[3];
  const float* W1    = (const float*)d_in[4];
  const float* b1    = (const float*)d_in[5];
  const float* W2    = (const float*)d_in[6];
  const float* b2    = (const float*)d_in[7];
  const float* Wout  = (const float*)d_in[8];
  const float* bout  = (const float*)d_in[9];
  float* out = (float*)d_out;

  const int N  = in_sizes[0] / EMB;   // 50000
  const int E0 = in_sizes[1] / 2;     // 100000
  const int E  = 2*E0 + N;            // 250000

  // workspace layout (fp32-word offsets; all 16B-aligned)
  float* base = (float*)d_ws;
  bf16_t* WcombT = (bf16_t*)base;                       // 768*256 bf16
  float*  bcomb  = base + 98304;                        // 768 w
  bf16_t* WoutT  = (bf16_t*)(base + 98304 + 768);       // 256*256 bf16
  bf16_t* xb     = (bf16_t*)(base + 131840);            // N*256 bf16
  bf16_t* Pb     = (bf16_t*)(base + 131840 + 6400000);  // N*768 bf16
  bf16_t* aggb   = (bf16_t*)(Pb + (size_t)N*768);       // N*256 bf16
  int* deg       = (int*)(aggb + (size_t)N*256);        // N
  int* cursor    = deg + N;                             // N
  int* flag      = cursor + N;                          // 1 (unused)
  int* off       = flag + 1;                            // N+1
  int* bj        = off + (N+1);                         // E
  // scratch for scan block sums: reuse aggb region (written only later by attn)
  int* bsum      = (int*)aggb;                          // <=1024 ints

  // fork-join side stream (created once; capture-legal: event fork/join pattern)
  static hipStream_t s1 = nullptr;
  static hipEvent_t evFork = nullptr, evJoin = nullptr;
  if (s1 == nullptr){
    hipStreamCreateWithFlags(&s1, hipStreamNonBlocking);
    hipEventCreateWithFlags(&evFork, hipEventDisableTiming);
    hipEventCreateWithFlags(&evJoin, hipEventDisableTiming);
  }

  // fork: edge pipeline on s1, dense pipeline on main stream
  hipEventRecord(evFork, stream);
  hipStreamWaitEvent(s1, evFork, 0);

  // --- s1: edge pipeline (independent of dense path until attn) ---
  hipMemsetAsync(deg, 0, (size_t)2*N*sizeof(int), s1);   // deg + cursor
  deg_kernel<<<(2*E0+255)/256,256,0,s1>>>(ei, deg, E0, N);
  const int nb = (N + 1023)/1024;
  scan1_kernel<<<nb,1024,0,s1>>>(deg, off, bsum, N);
  scan2_kernel<<<1,1024,0,s1>>>(bsum, off, nb, N);
  scan3_kernel<<<(N+255)/256,256,0,s1>>>(off, bsum, N);
  scatter_kernel<<<(E+255)/256,256,0,s1>>>(ei, off, cursor, bj, E0, N);

  // --- main: dense pipeline ---
  cvt_x_kernel<<<((N*EMB/4)+255)/256,256,0,stream>>>(x, xb, N*EMB/4);
  prep_weights<<<dim3(3,257),256,0,stream>>>(Wkqv, bkqv, W1, WcombT, bcomb);
  prep_wout<<<256,256,0,stream>>>(Wout, WoutT);
  const int nm256 = (((N+255)/256) + 7) & ~7;   // 200 m-strips of 256
  mfma_gemm256<<<nm256*3,1024,0,stream>>>(xb, WcombT, bcomb, Pb, N, 768);

  // join: attn needs Pb (main) + bj/off (s1); gemm1 needs deg (s1)
  hipEventRecord(evJoin, s1);
  hipStreamWaitEvent(stream, evJoin, 0);

  fused_attn_kernel<<<(N+3)/4,256,0,stream>>>(Pb, bj, off, b1, W2, b2, aggb, N);
  const int nm128 = (((N+127)/128) + 7) & ~7;   // 392 m-strips of 128
  mfma_gemm_m1<<<nm128,512,0,stream>>>(aggb, WoutT, bout, out, N, 256, deg, x);
}

// Round 9
// 284.254 us; speedup vs baseline: 1.1218x; 1.1060x over previous
//
#include <hip/hip_runtime.h>
#include <hip/hip_bf16.h>

#define EMB 256

typedef __bf16 bf16_t;
typedef __attribute__((ext_vector_type(8))) __bf16 bf16x8;
typedef __attribute__((ext_vector_type(4))) __bf16 bf16x4;
typedef __attribute__((ext_vector_type(4))) float floatx4;

// ---------- helpers ----------
__device__ __forceinline__ int eidx(const int* __restrict__ p, int is64, long long k){
  return is64 ? p[2*k] : p[(int)k];
}
// async global->LDS, 16B per lane; LDS base must be WAVE-UNIFORM, lands at base + lane*16
__device__ __forceinline__ void async_load16(const void* g, void* l){
  __builtin_amdgcn_global_load_lds(
      (const __attribute__((address_space(1))) unsigned int*)g,
      (__attribute__((address_space(3))) unsigned int*)l,
      16, 0, 0);
}
__device__ __forceinline__ float4 cvt4(bf16x4 v){
  return make_float4((float)v.x, (float)v.y, (float)v.z, (float)v.w);
}
// inline dtype detect: int64 edge_index -> high words of first entries are 0
__device__ __forceinline__ int detect64(const int* __restrict__ ei){
  return ((ei[1] | ei[3] | ei[5] | ei[7]) == 0) ? 1 : 0;
}

// ---------- x -> bf16 ----------
__global__ void cvt_x_kernel(const float* __restrict__ x, bf16_t* __restrict__ xb, int n4){
  int t = blockIdx.x*blockDim.x + threadIdx.x;
  if (t >= n4) return;
  const float4 v = *(const float4*)(x + (size_t)t*4);
  bf16x4 o = { (bf16_t)v.x, (bf16_t)v.y, (bf16_t)v.z, (bf16_t)v.w };
  *(bf16x4*)(xb + (size_t)t*4) = o;
}

// ---------- fold W1 into Wkqv; emit TRANSPOSED bf16 WcombT[768][256] + fp32 bcomb[768] ----------
// Output column layout (KV-PACKED): cols [0,256) = q (h*128+d);
// cols [256,768): r = n-256, h = r>>8, g = (r&255)>>3, half = (r>>2)&1, dd = r&3, d = g*4+dd;
//   half 0 -> k_scaled[h][d], half 1 -> v[h][d].
__global__ void prep_weights(const float* __restrict__ Wkqv, const float* __restrict__ bkqv,
                             const float* __restrict__ W1,
                             bf16_t* __restrict__ WcombT, float* __restrict__ bcomb){
  int n = blockIdx.x * blockDim.x + threadIdx.x;   // 0..767 (output col, permuted layout)
  int c = blockIdx.y;                              // 0..256 (k index; 256 = bias)
  if (n >= 768) return;
  const float rs = rsqrtf(128.0f);
  bool isBias = (c == 256);
  const float* arow = isBias ? bkqv : (Wkqv + (size_t)c*768);
  float val;
  if (n < 256){                       // q
    int h = n >> 7, d = n & 127;
    float s = 0.f;
    for (int t = 0; t < 128; ++t)
      s = fmaf(arow[h*128 + t], W1[(size_t)(128 + t)*128 + d], s);
    val = s;
  } else {
    int r = n - 256;
    int h = r >> 8, t8 = r & 255;
    int g = t8 >> 3, half = (t8 >> 2) & 1, dd = t8 & 3;
    int d = g*4 + dd;
    if (half == 0){                   // k (scaled)
      float s = 0.f;
      for (int t = 0; t < 128; ++t)
        s = fmaf(arow[256 + h*128 + t], W1[(size_t)t*128 + d], s);
      val = s * rs;
    } else {                          // v passthrough
      val = arow[512 + h*128 + d];
    }
  }
  if (isBias) bcomb[n] = val;
  else        WcombT[(size_t)n*256 + c] = (bf16_t)val;
}

// ---------- Wout -> transposed bf16 WoutT[256][256] ----------
__global__ void prep_wout(const float* __restrict__ W, bf16_t* __restrict__ Wt){
  int t = blockIdx.x*blockDim.x + threadIdx.x;  // 65536
  int n = t & 255, c = t >> 8;
  Wt[(size_t)n*256 + c] = (bf16_t)W[(size_t)c*256 + n];
}

// ---------- degree count over the 2*E0 non-self edges (dst side) ----------
__global__ void deg_kernel(const int* __restrict__ ei,
                           int* __restrict__ deg, int E0, int Nn){
  int t = blockIdx.x*blockDim.x + threadIdx.x;
  if (t >= 2*E0) return;
  int is64 = detect64(ei);
  int i = (t < E0) ? eidx(ei,is64,(long long)E0+t) : eidx(ei,is64,t-E0);
  i = min(max(i,0), Nn-1);
  atomicAdd(deg + i, 1);
}

// ---------- hierarchical exclusive scan of (deg+1) -> off[0..N] ----------
__global__ __launch_bounds__(1024) void scan1_kernel(const int* __restrict__ deg,
                                                     int* __restrict__ off,
                                                     int* __restrict__ bsum, int N){
  __shared__ int wsum[16];
  int tid = threadIdx.x, lane = tid & 63, w = tid >> 6;
  int i = blockIdx.x*1024 + tid;
  int v = (i < N) ? (deg[i] + 1) : 0;
  int incl = v;
  #pragma unroll
  for (int o = 1; o < 64; o <<= 1){
    int t = __shfl_up(incl, o, 64);
    if (lane >= o) incl += t;
  }
  if (lane == 63) wsum[w] = incl;
  __syncthreads();
  if (w == 0 && lane < 16){
    int sv = wsum[lane];
    #pragma unroll
    for (int o = 1; o < 16; o <<= 1){
      int t = __shfl_up(sv, o, 64);
      if (lane >= o) sv += t;
    }
    wsum[lane] = sv;
  }
  __syncthreads();
  int wpref = (w == 0) ? 0 : wsum[w-1];
  if (i < N) off[i] = wpref + incl - v;          // block-local exclusive
  if (tid == 1023) bsum[blockIdx.x] = wpref + incl;  // block total
}

__global__ __launch_bounds__(1024) void scan2_kernel(int* __restrict__ bsum,
                                                     int* __restrict__ off, int nb, int N){
  __shared__ int wsum[16];
  int tid = threadIdx.x, lane = tid & 63, w = tid >> 6;
  int v = (tid < nb) ? bsum[tid] : 0;
  int incl = v;
  #pragma unroll
  for (int o = 1; o < 64; o <<= 1){
    int t = __shfl_up(incl, o, 64);
    if (lane >= o) incl += t;
  }
  if (lane == 63) wsum[w] = incl;
  __syncthreads();
  if (w == 0 && lane < 16){
    int sv = wsum[lane];
    #pragma unroll
    for (int o = 1; o < 16; o <<= 1){
      int t = __shfl_up(sv, o, 64);
      if (lane >= o) sv += t;
    }
    wsum[lane] = sv;
  }
  __syncthreads();
  int wpref = (w == 0) ? 0 : wsum[w-1];
  if (tid < nb) bsum[tid] = wpref + incl - v;    // exclusive block offsets
  if (tid == 1023) off[N] = wpref + incl;        // grand total
}

__global__ void scan3_kernel(int* __restrict__ off, const int* __restrict__ bsum, int N){
  int i = blockIdx.x*256 + threadIdx.x;
  if (i < N) off[i] += bsum[i >> 10];
}

// ---------- scatter source index j into CSR buckets (incl. self-loops) ----------
__global__ void scatter_kernel(const int* __restrict__ ei,
                               const int* __restrict__ off, int* __restrict__ cursor,
                               int* __restrict__ bj, int E0, int Nn){
  int e = blockIdx.x*blockDim.x + threadIdx.x;
  int E = 2*E0 + Nn;
  if (e >= E) return;
  int is64 = detect64(ei);
  int j, i;
  if (e < E0){ j = eidx(ei,is64,e); i = eidx(ei,is64,(long long)E0+e); }
  else if (e < 2*E0){ int t = e - E0; i = eidx(ei,is64,t); j = eidx(ei,is64,(long long)E0+t); }
  else { i = j = e - 2*E0; }
  i = min(max(i,0), Nn-1); j = min(max(j,0), Nn-1);
  int pos = atomicAdd(cursor + i, 1);
  bj[off[i] + pos] = j;
}

// ---------- 256x256-tile bf16 MFMA GEMM (MODE 0), K=256 -- round-6 best, verbatim ----------
__global__ __launch_bounds__(1024, 4) void mfma_gemm256(
    const bf16_t* __restrict__ A, const bf16_t* __restrict__ Bt,
    const float* __restrict__ bias, bf16_t* __restrict__ C,
    int M, int N)
{
  __shared__ bf16_t As[2][256*32];   // 16 KB each
  __shared__ bf16_t Bs[2][256*32];
  const int tid = threadIdx.x;
  const int wave = tid >> 6, lane = tid & 63;   // wave 0..15
  const int row16 = lane & 15, quad = lane >> 4;

  const int nn = N >> 8;               // n-strips of 256
  const int bid = blockIdx.x;
  const int strip = bid / (8*nn);
  const int inner = bid % (8*nn);
  const int m0 = (strip*8 + (inner & 7)) * 256;
  const int n0 = (inner >> 3) * 256;
  const int wm  = (wave >> 2) * 64;    // 0,64,128,192
  const int wnq = (wave & 3) * 64;     // 0,64,128,192

  const int gm0 = min(m0 + wave*16 + row16, M-1);
  const int gn0 = n0 + wave*16 + row16;

  async_load16(A  + (size_t)gm0*256 + quad*8, (char*)As[0] + wave*1024);
  async_load16(Bt + (size_t)gn0*256 + quad*8, (char*)Bs[0] + wave*1024);

  floatx4 acc[4][4];
  #pragma unroll
  for (int a=0;a<4;++a)
    #pragma unroll
    for (int b=0;b<4;++b) acc[a][b] = (floatx4){0.f,0.f,0.f,0.f};

  #pragma unroll
  for (int kt = 0; kt < 8; ++kt){
    const int cur = kt & 1, nxt = cur ^ 1;
    const int k1 = (kt+1)*32;

    __syncthreads();   // buffer[cur] staged; buffer[nxt] free

    if (kt < 7){
      async_load16(A  + (size_t)gm0*256 + k1 + quad*8, (char*)As[nxt] + wave*1024);
      async_load16(Bt + (size_t)gn0*256 + k1 + quad*8, (char*)Bs[nxt] + wave*1024);
    }

    bf16x8 af[4], bfr[4];
    #pragma unroll
    for (int t = 0; t < 4; ++t){
      af[t]  = *(const bf16x8*)((const char*)As[cur] + ((wm>>4)+t)*1024 + lane*16);
      bfr[t] = *(const bf16x8*)((const char*)Bs[cur] + ((wnq>>4)+t)*1024 + lane*16);
    }
    // SWAPPED operands: D tile gets row=n_local, col=m_local
    #pragma unroll
    for (int mt=0;mt<4;++mt)
      #pragma unroll
      for (int nt=0;nt<4;++nt)
        acc[mt][nt] = __builtin_amdgcn_mfma_f32_16x16x32_bf16(bfr[nt], af[mt], acc[mt][nt], 0,0,0);
  }

  // epilogue: lane holds m = lane&15, n = quad*4 + {0..3} per tile -> 8B stores
  float4 b4[4];
  #pragma unroll
  for (int nt=0;nt<4;++nt)
    b4[nt] = *(const float4*)(bias + n0 + wnq + nt*16 + quad*4);

  #pragma unroll
  for (int mt=0;mt<4;++mt){
    const int m = m0 + wm + mt*16 + row16;
    if (m >= M) continue;
    #pragma unroll
    for (int nt=0;nt<4;++nt){
      const int nb = n0 + wnq + nt*16 + quad*4;
      bf16x4 o = { (bf16_t)(acc[mt][nt][0] + b4[nt].x),
                   (bf16_t)(acc[mt][nt][1] + b4[nt].y),
                   (bf16_t)(acc[mt][nt][2] + b4[nt].z),
                   (bf16_t)(acc[mt][nt][3] + b4[nt].w) };
      *(bf16x4*)(C + (size_t)m*N + nb) = o;
    }
  }
}

// ---------- 256x256-tile GEMM (MODE 1), N=256: gemm256 skeleton + fused epilogue ----------
// out = relu(AB + (deg[m]+1)*bias[n]) + xres[m*256+n], fp32 out.
// Grid = 200 blocks (25 m-octets) -> SINGLE scheduling round (no tail);
// aggb read once, full WoutT panel per block, identical staging/MFMA order.
__global__ __launch_bounds__(1024, 4) void mfma_gemm_m1(
    const bf16_t* __restrict__ A, const bf16_t* __restrict__ Bt,
    const float* __restrict__ bias, float* __restrict__ C,
    int M,
    const int* __restrict__ deg, const float* __restrict__ xres)
{
  __shared__ bf16_t As[2][256*32];   // 16 KB each
  __shared__ bf16_t Bs[2][256*32];
  const int tid = threadIdx.x;
  const int wave = tid >> 6, lane = tid & 63;   // wave 0..15
  const int row16 = lane & 15, quad = lane >> 4;

  // XCD swizzle over m-strips (single n-strip, N=256)
  const int bid = blockIdx.x;
  const int m0 = ((bid >> 3)*8 + (bid & 7)) * 256;
  const int wm  = (wave >> 2) * 64;    // 0,64,128,192
  const int wnq = (wave & 3) * 64;     // 0,64,128,192

  const int gm0 = min(m0 + wave*16 + row16, M-1);
  const int gn0 = wave*16 + row16;     // B rows 0..255 = full WoutT panel

  async_load16(A  + (size_t)gm0*256 + quad*8, (char*)As[0] + wave*1024);
  async_load16(Bt + (size_t)gn0*256 + quad*8, (char*)Bs[0] + wave*1024);

  floatx4 acc[4][4];
  #pragma unroll
  for (int a=0;a<4;++a)
    #pragma unroll
    for (int b=0;b<4;++b) acc[a][b] = (floatx4){0.f,0.f,0.f,0.f};

  #pragma unroll
  for (int kt = 0; kt < 8; ++kt){
    const int cur = kt & 1, nxt = cur ^ 1;
    const int k1 = (kt+1)*32;

    __syncthreads();   // buffer[cur] staged; buffer[nxt] free

    if (kt < 7){
      async_load16(A  + (size_t)gm0*256 + k1 + quad*8, (char*)As[nxt] + wave*1024);
      async_load16(Bt + (size_t)gn0*256 + k1 + quad*8, (char*)Bs[nxt] + wave*1024);
    }

    bf16x8 af[4], bfr[4];
    #pragma unroll
    for (int t = 0; t < 4; ++t){
      af[t]  = *(const bf16x8*)((const char*)As[cur] + ((wm>>4)+t)*1024 + lane*16);
      bfr[t] = *(const bf16x8*)((const char*)Bs[cur] + ((wnq>>4)+t)*1024 + lane*16);
    }
    #pragma unroll
    for (int mt=0;mt<4;++mt)
      #pragma unroll
      for (int nt=0;nt<4;++nt)
        acc[mt][nt] = __builtin_amdgcn_mfma_f32_16x16x32_bf16(bfr[nt], af[mt], acc[mt][nt], 0,0,0);
  }

  // epilogue: lane holds m = lane&15, n = quad*4 + {0..3} per tile
  float4 b4[4];
  #pragma unroll
  for (int nt=0;nt<4;++nt)
    b4[nt] = *(const float4*)(bias + wnq + nt*16 + quad*4);

  #pragma unroll
  for (int mt=0;mt<4;++mt){
    const int m = m0 + wm + mt*16 + row16;
    if (m >= M) continue;
    const float dg = (float)(deg[m]+1);
    #pragma unroll
    for (int nt=0;nt<4;++nt){
      const int nb = wnq + nt*16 + quad*4;
      const float4 xr = *(const float4*)(xres + (size_t)m*256 + nb);
      float4 o;
      o.x = fmaxf(acc[mt][nt][0] + dg*b4[nt].x, 0.f) + xr.x;
      o.y = fmaxf(acc[mt][nt][1] + dg*b4[nt].y, 0.f) + xr.y;
      o.z = fmaxf(acc[mt][nt][2] + dg*b4[nt].z, 0.f) + xr.z;
      o.w = fmaxf(acc[mt][nt][3] + dg*b4[nt].w, 0.f) + xr.w;
      *(float4*)(C + (size_t)m*256 + nb) = o;
    }
  }
}

// ---------- fused attention: score + online softmax + aggregate, one wave per node ----------
__device__ __forceinline__ float score4(bf16x8 kvv, float4 qv, float4 b1v, float4 w2v){
  return fmaxf(qv.x+(float)kvv[0]+b1v.x, 0.f)*w2v.x
       + fmaxf(qv.y+(float)kvv[1]+b1v.y, 0.f)*w2v.y
       + fmaxf(qv.z+(float)kvv[2]+b1v.z, 0.f)*w2v.z
       + fmaxf(qv.w+(float)kvv[3]+b1v.w, 0.f)*w2v.w;
}
__device__ __forceinline__ float hredux(float p){
  #pragma unroll
  for (int o = 16; o >= 1; o >>= 1)
    p += __shfl_xor(p, o, 64);
  return p;
}
__global__ __launch_bounds__(256) void fused_attn_kernel(
    const bf16_t* __restrict__ P, const int* __restrict__ bj, const int* __restrict__ off,
    const float* __restrict__ b1, const float* __restrict__ W2, const float* __restrict__ b2,
    bf16_t* __restrict__ aggb, int Nn)
{
  int i = blockIdx.x * (blockDim.x >> 6) + (threadIdx.x >> 6);
  if (i >= Nn) return;
  int lane = threadIdx.x & 63;
  int h = lane >> 5, g = lane & 31, d = g * 4;

  const float4 qv  = cvt4(*(const bf16x4*)(P + (size_t)i*768 + h*128 + d));
  const float4 b1v = *(const float4*)(b1 + d);
  const float4 w2v = *(const float4*)(W2 + d);
  const float b2v  = b2[0];
  const bf16_t* __restrict__ Pkv = P + 256 + h*256 + g*8;

  float m = -3.0e38f, s = 0.f;
  float4 acc = make_float4(0.f,0.f,0.f,0.f);
  const int s0 = off[i], s1 = off[i+1], s1m1 = s1 - 1;

  for (int t = s0; t < s1; t += 4){
    const int cnt = s1 - t;                 // >= 1
    const int jA = bj[t];
    const int jB = bj[min(t+1, s1m1)];
    const int jC = bj[min(t+2, s1m1)];
    const int jD = bj[min(t+3, s1m1)];
    const bf16x8 kA = *(const bf16x8*)(Pkv + (size_t)jA*768);
    const bf16x8 kB = *(const bf16x8*)(Pkv + (size_t)jB*768);
    const bf16x8 kC = *(const bf16x8*)(Pkv + (size_t)jC*768);
    const bf16x8 kD = *(const bf16x8*)(Pkv + (size_t)jD*768);
    float pA = hredux(score4(kA, qv, b1v, w2v));
    float pB = hredux(score4(kB, qv, b1v, w2v));
    float pC = hredux(score4(kC, qv, b1v, w2v));
    float pD = hredux(score4(kD, qv, b1v, w2v));
    const float aA = pA + b2v;
    const float aB = (cnt > 1) ? pB + b2v : -3.0e38f;
    const float aC = (cnt > 2) ? pC + b2v : -3.0e38f;
    const float aD = (cnt > 3) ? pD + b2v : -3.0e38f;
    const float amax = fmaxf(fmaxf(aA, aB), fmaxf(aC, aD));
    const float mn = fmaxf(m, amax);
    const float sc = __expf(m - mn);
    const float eA = __expf(aA - mn);       // masked lanes -> exp(-inf) = 0
    const float eB = __expf(aB - mn);
    const float eC = __expf(aC - mn);
    const float eD = __expf(aD - mn);
    s = s*sc + ((eA + eB) + (eC + eD));
    acc.x = acc.x*sc + ((eA*(float)kA[4] + eB*(float)kB[4]) + (eC*(float)kC[4] + eD*(float)kD[4]));
    acc.y = acc.y*sc + ((eA*(float)kA[5] + eB*(float)kB[5]) + (eC*(float)kC[5] + eD*(float)kD[5]));
    acc.z = acc.z*sc + ((eA*(float)kA[6] + eB*(float)kB[6]) + (eC*(float)kC[6] + eD*(float)kD[6]));
    acc.w = acc.w*sc + ((eA*(float)kA[7] + eB*(float)kB[7]) + (eC*(float)kC[7] + eD*(float)kD[7]));
    m = mn;
  }
  float inv = 1.f / (s + 1e-16f);
  bf16x4 ob = { (bf16_t)(acc.x*inv), (bf16_t)(acc.y*inv), (bf16_t)(acc.z*inv), (bf16_t)(acc.w*inv) };
  *(bf16x4*)(aggb + (size_t)i*256 + h*128 + d) = ob;
}

// ---------- launch ----------
extern "C" void kernel_launch(void* const* d_in, const int* in_sizes, int n_in,
                              void* d_out, int out_size, void* d_ws, size_t ws_size,
                              hipStream_t stream)
{
  const float* x     = (const float*)d_in[0];
  const int*   ei    = (const int*)d_in[1];
  const float* Wkqv  = (const float*)d_in[2];
  const float* bkqv  = (const float*)d_in[3];
  const float* W1    = (const float*)d_in[4];
  const float* b1    = (const float*)d_in[5];
  const float* W2    = (const float*)d_in[6];
  const float* b2    = (const float*)d_in[7];
  const float* Wout  = (const float*)d_in[8];
  const float* bout  = (const float*)d_in[9];
  float* out = (float*)d_out;

  const int N  = in_sizes[0] / EMB;   // 50000
  const int E0 = in_sizes[1] / 2;     // 100000
  const int E  = 2*E0 + N;            // 250000

  // workspace layout (fp32-word offsets; all 16B-aligned)
  float* base = (float*)d_ws;
  bf16_t* WcombT = (bf16_t*)base;                       // 768*256 bf16
  float*  bcomb  = base + 98304;                        // 768 w
  bf16_t* WoutT  = (bf16_t*)(base + 98304 + 768);       // 256*256 bf16
  bf16_t* xb     = (bf16_t*)(base + 131840);            // N*256 bf16
  bf16_t* Pb     = (bf16_t*)(base + 131840 + 6400000);  // N*768 bf16
  bf16_t* aggb   = (bf16_t*)(Pb + (size_t)N*768);       // N*256 bf16
  int* deg       = (int*)(aggb + (size_t)N*256);        // N
  int* cursor    = deg + N;                             // N
  int* flag      = cursor + N;                          // 1 (unused)
  int* off       = flag + 1;                            // N+1
  int* bj        = off + (N+1);                         // E
  // scratch for scan block sums: reuse aggb region (written only later by attn)
  int* bsum      = (int*)aggb;                          // <=1024 ints

  hipMemsetAsync(deg, 0, (size_t)2*N*sizeof(int), stream);  // deg + cursor

  cvt_x_kernel<<<((N*EMB/4)+255)/256,256,0,stream>>>(x, xb, N*EMB/4);
  prep_weights<<<dim3(3,257),256,0,stream>>>(Wkqv, bkqv, W1, WcombT, bcomb);
  prep_wout<<<256,256,0,stream>>>(Wout, WoutT);

  deg_kernel<<<(2*E0+255)/256,256,0,stream>>>(ei, deg, E0, N);
  const int nb = (N + 1023)/1024;
  scan1_kernel<<<nb,1024,0,stream>>>(deg, off, bsum, N);
  scan2_kernel<<<1,1024,0,stream>>>(bsum, off, nb, N);
  scan3_kernel<<<(N+255)/256,256,0,stream>>>(off, bsum, N);
  scatter_kernel<<<(E+255)/256,256,0,stream>>>(ei, off, cursor, bj, E0, N);

  // gemm<0>: 256x256 tiles (m-strips of 256, padded to mult of 8 for XCD swizzle)
  const int nm256 = (((N+255)/256) + 7) & ~7;   // 200
  mfma_gemm256<<<nm256*3,1024,0,stream>>>(xb, WcombT, bcomb, Pb, N, 768);
  fused_attn_kernel<<<(N+3)/4,256,0,stream>>>(Pb, bj, off, b1, W2, b2, aggb, N);
  // gemm<1>: 256x256 tiles, single n-strip -> 200 blocks, one scheduling round
  mfma_gemm_m1<<<nm256,1024,0,stream>>>(aggb, WoutT, bout, out, N, deg, x);
}

// Round 10
// 279.688 us; speedup vs baseline: 1.1401x; 1.0163x over previous
//
#include <hip/hip_runtime.h>
#include <hip/hip_bf16.h>

#define EMB 256

typedef __bf16 bf16_t;
typedef __attribute__((ext_vector_type(8))) __bf16 bf16x8;
typedef __attribute__((ext_vector_type(4))) __bf16 bf16x4;
typedef __attribute__((ext_vector_type(4))) float floatx4;

// ---------- helpers ----------
__device__ __forceinline__ int eidx(const int* __restrict__ p, int is64, long long k){
  return is64 ? p[2*k] : p[(int)k];
}
// async global->LDS, 16B per lane; LDS base must be WAVE-UNIFORM, lands at base + lane*16
__device__ __forceinline__ void async_load16(const void* g, void* l){
  __builtin_amdgcn_global_load_lds(
      (const __attribute__((address_space(1))) unsigned int*)g,
      (__attribute__((address_space(3))) unsigned int*)l,
      16, 0, 0);
}
__device__ __forceinline__ float4 cvt4(bf16x4 v){
  return make_float4((float)v.x, (float)v.y, (float)v.z, (float)v.w);
}
// inline dtype detect: int64 edge_index -> high words of first entries are 0
__device__ __forceinline__ int detect64(const int* __restrict__ ei){
  return ((ei[1] | ei[3] | ei[5] | ei[7]) == 0) ? 1 : 0;
}

// ---------- fused prep: cvt_x | prep_weights | prep_wout | deg (block-partitioned) ----------
// Four independent preprocessing jobs in ONE launch (saves 3 launch gaps).
__global__ __launch_bounds__(256) void prep_all_kernel(
    const float* __restrict__ x, bf16_t* __restrict__ xb, int n4,
    const float* __restrict__ Wkqv, const float* __restrict__ bkqv,
    const float* __restrict__ W1, bf16_t* __restrict__ WcombT, float* __restrict__ bcomb,
    const float* __restrict__ Wout, bf16_t* __restrict__ WoutT,
    const int* __restrict__ ei, int* __restrict__ deg, int E0, int Nn,
    int G_CVT, int G_PW, int G_WO)
{
  const int bid = blockIdx.x, tid = threadIdx.x;
  if (bid < G_CVT){
    // ---- x -> bf16 ----
    int t = bid*256 + tid;
    if (t >= n4) return;
    const float4 v = *(const float4*)(x + (size_t)t*4);
    bf16x4 o = { (bf16_t)v.x, (bf16_t)v.y, (bf16_t)v.z, (bf16_t)v.w };
    *(bf16x4*)(xb + (size_t)t*4) = o;
  } else if (bid < G_CVT + G_PW){
    // ---- fold W1 into Wkqv -> WcombT[768][256] + bcomb[768] (KV-PACKED cols) ----
    int b2 = bid - G_CVT;          // 0..770
    int c  = b2 / 3;               // 0..256 (256 = bias)
    int n  = (b2 % 3)*256 + tid;   // 0..767
    const float rs = rsqrtf(128.0f);
    bool isBias = (c == 256);
    const float* arow = isBias ? bkqv : (Wkqv + (size_t)c*768);
    float val;
    if (n < 256){                       // q
      int h = n >> 7, d = n & 127;
      float s = 0.f;
      for (int t2 = 0; t2 < 128; ++t2)
        s = fmaf(arow[h*128 + t2], W1[(size_t)(128 + t2)*128 + d], s);
      val = s;
    } else {
      int r = n - 256;
      int h = r >> 8, t8 = r & 255;
      int g = t8 >> 3, half = (t8 >> 2) & 1, dd = t8 & 3;
      int d = g*4 + dd;
      if (half == 0){                   // k (scaled)
        float s = 0.f;
        for (int t2 = 0; t2 < 128; ++t2)
          s = fmaf(arow[256 + h*128 + t2], W1[(size_t)t2*128 + d], s);
        val = s * rs;
      } else {                          // v passthrough
        val = arow[512 + h*128 + d];
      }
    }
    if (isBias) bcomb[n] = val;
    else        WcombT[(size_t)n*256 + c] = (bf16_t)val;
  } else if (bid < G_CVT + G_PW + G_WO){
    // ---- Wout -> transposed bf16 WoutT ----
    int t = (bid - G_CVT - G_PW)*256 + tid;  // 0..65535
    int n = t & 255, c = t >> 8;
    WoutT[(size_t)n*256 + c] = (bf16_t)Wout[(size_t)c*256 + n];
  } else {
    // ---- degree count (dst side of the 2*E0 undirected edges) ----
    int t = (bid - G_CVT - G_PW - G_WO)*256 + tid;
    if (t >= 2*E0) return;
    int is64 = detect64(ei);
    int i = (t < E0) ? eidx(ei,is64,(long long)E0+t) : eidx(ei,is64,t-E0);
    i = min(max(i,0), Nn-1);
    atomicAdd(deg + i, 1);
  }
}

// ---------- hierarchical exclusive scan of (deg+1): scan1 (local) + scan2 (block sums) ----------
// Final off[i] = off[i] + bsum[i>>10], applied ON THE FLY by scatter/attn (scan3 eliminated).
__global__ __launch_bounds__(1024) void scan1_kernel(const int* __restrict__ deg,
                                                     int* __restrict__ off,
                                                     int* __restrict__ bsum, int N){
  __shared__ int wsum[16];
  int tid = threadIdx.x, lane = tid & 63, w = tid >> 6;
  int i = blockIdx.x*1024 + tid;
  int v = (i < N) ? (deg[i] + 1) : 0;
  int incl = v;
  #pragma unroll
  for (int o = 1; o < 64; o <<= 1){
    int t = __shfl_up(incl, o, 64);
    if (lane >= o) incl += t;
  }
  if (lane == 63) wsum[w] = incl;
  __syncthreads();
  if (w == 0 && lane < 16){
    int sv = wsum[lane];
    #pragma unroll
    for (int o = 1; o < 16; o <<= 1){
      int t = __shfl_up(sv, o, 64);
      if (lane >= o) sv += t;
    }
    wsum[lane] = sv;
  }
  __syncthreads();
  int wpref = (w == 0) ? 0 : wsum[w-1];
  if (i < N) off[i] = wpref + incl - v;          // block-local exclusive
  if (tid == 1023) bsum[blockIdx.x] = wpref + incl;  // block total
}

__global__ __launch_bounds__(1024) void scan2_kernel(int* __restrict__ bsum,
                                                     int* __restrict__ off, int nb, int N){
  __shared__ int wsum[16];
  int tid = threadIdx.x, lane = tid & 63, w = tid >> 6;
  int v = (tid < nb) ? bsum[tid] : 0;
  int incl = v;
  #pragma unroll
  for (int o = 1; o < 64; o <<= 1){
    int t = __shfl_up(incl, o, 64);
    if (lane >= o) incl += t;
  }
  if (lane == 63) wsum[w] = incl;
  __syncthreads();
  if (w == 0 && lane < 16){
    int sv = wsum[lane];
    #pragma unroll
    for (int o = 1; o < 16; o <<= 1){
      int t = __shfl_up(sv, o, 64);
      if (lane >= o) sv += t;
    }
    wsum[lane] = sv;
  }
  __syncthreads();
  int wpref = (w == 0) ? 0 : wsum[w-1];
  if (tid < nb) bsum[tid] = wpref + incl - v;    // exclusive block offsets
  if (tid == 1023) off[N] = wpref + incl;        // grand total (FINAL, no bsum add)
}

// ---------- scatter source index j into CSR buckets (incl. self-loops); off+bsum on the fly ----------
__global__ void scatter_kernel(const int* __restrict__ ei,
                               const int* __restrict__ off, const int* __restrict__ bsum,
                               int* __restrict__ cursor,
                               int* __restrict__ bj, int E0, int Nn){
  int e = blockIdx.x*blockDim.x + threadIdx.x;
  int E = 2*E0 + Nn;
  if (e >= E) return;
  int is64 = detect64(ei);
  int j, i;
  if (e < E0){ j = eidx(ei,is64,e); i = eidx(ei,is64,(long long)E0+e); }
  else if (e < 2*E0){ int t = e - E0; i = eidx(ei,is64,t); j = eidx(ei,is64,(long long)E0+t); }
  else { i = j = e - 2*E0; }
  i = min(max(i,0), Nn-1); j = min(max(j,0), Nn-1);
  int pos = atomicAdd(cursor + i, 1);
  bj[off[i] + bsum[i>>10] + pos] = j;
}

// ---------- 256x256-tile bf16 MFMA GEMM, K=256, BK=64 ----------
// Proven r6/r9 skeleton with BK doubled 32->64: halves the per-block
// __syncthreads/vmcnt(0) drain count (16->8) and doubles compute per drain
// (32 MFMA vs 16). LDS 128 KB dbuf -> 1 block x 16 waves/CU (50% occ, up from
// measured 28%). Fragment layout/staging/MFMA order unchanged -> same numerics.
// MODE 0: C(bf16) = AB + bias[n]       (N = 768, 3 n-strips)
// MODE 1: C(fp32) = relu(AB + (deg[m]+1)*bias[n]) + xres[m*N+n]   (N = 256)
template<int MODE, typename OutT>
__global__ __launch_bounds__(1024, 4) void mfma_gemm256T(
    const bf16_t* __restrict__ A, const bf16_t* __restrict__ Bt,
    const float* __restrict__ bias, OutT* __restrict__ C,
    int M, int N,
    const int* __restrict__ deg, const float* __restrict__ xres)
{
  __shared__ bf16_t As[2][256*64];   // 32 KB each
  __shared__ bf16_t Bs[2][256*64];
  const int tid = threadIdx.x;
  const int wave = tid >> 6, lane = tid & 63;   // wave 0..15
  const int row16 = lane & 15, quad = lane >> 4;

  // XCD swizzle: m-strip octets round-robin; n fastest per octet
  const int nn = N >> 8;               // n-strips of 256 (3 or 1)
  const int bid = blockIdx.x;
  const int strip = bid / (8*nn);
  const int inner = bid % (8*nn);
  const int m0 = (strip*8 + (inner & 7)) * 256;
  const int n0 = (inner >> 3) * 256;
  const int wm  = (wave >> 2) * 64;    // 0,64,128,192
  const int wnq = (wave & 3) * 64;     // 0,64,128,192

  // staging: wave w owns fragment row w (16 rows) of A and B, both k-subtiles
  const int gm0 = min(m0 + wave*16 + row16, M-1);
  const int gn0 = n0 + wave*16 + row16;
  const bf16_t* gA = A  + (size_t)gm0*256 + quad*8;
  const bf16_t* gB = Bt + (size_t)gn0*256 + quad*8;

  // LDS fragment (fr, ks) lives at byte offset (fr*2+ks)*1024
  #define STAGE64(buf, kb) do{ \
    async_load16(gA + (kb),      (char*)As[buf] + (wave*2+0)*1024); \
    async_load16(gA + (kb) + 32, (char*)As[buf] + (wave*2+1)*1024); \
    async_load16(gB + (kb),      (char*)Bs[buf] + (wave*2+0)*1024); \
    async_load16(gB + (kb) + 32, (char*)Bs[buf] + (wave*2+1)*1024); }while(0)

  // prologue: stage k-tile 0 into buffer 0
  STAGE64(0, 0);

  floatx4 acc[4][4];
  #pragma unroll
  for (int a=0;a<4;++a)
    #pragma unroll
    for (int b=0;b<4;++b) acc[a][b] = (floatx4){0.f,0.f,0.f,0.f};

  #pragma unroll
  for (int kt = 0; kt < 4; ++kt){
    const int cur = kt & 1, nxt = cur ^ 1;

    __syncthreads();   // buffer[cur] staged; buffer[nxt] free

    if (kt < 3) STAGE64(nxt, (kt+1)*64);

    #pragma unroll
    for (int kk = 0; kk < 2; ++kk){
      bf16x8 af[4], bfr[4];
      #pragma unroll
      for (int t = 0; t < 4; ++t){
        af[t]  = *(const bf16x8*)((const char*)As[cur] + (((wm>>4)+t)*2 + kk)*1024 + lane*16);
        bfr[t] = *(const bf16x8*)((const char*)Bs[cur] + (((wnq>>4)+t)*2 + kk)*1024 + lane*16);
      }
      // SWAPPED operands: D tile gets row=n_local, col=m_local
      #pragma unroll
      for (int mt=0;mt<4;++mt)
        #pragma unroll
        for (int nt=0;nt<4;++nt)
          acc[mt][nt] = __builtin_amdgcn_mfma_f32_16x16x32_bf16(bfr[nt], af[mt], acc[mt][nt], 0,0,0);
    }
  }
  #undef STAGE64

  // epilogue: lane holds m = lane&15, n = quad*4 + {0..3} per tile -> vector stores
  float4 b4[4];
  #pragma unroll
  for (int nt=0;nt<4;++nt)
    b4[nt] = *(const float4*)(bias + n0 + wnq + nt*16 + quad*4);

  #pragma unroll
  for (int mt=0;mt<4;++mt){
    const int m = m0 + wm + mt*16 + row16;
    if (m >= M) continue;
    const float dg = (MODE==1) ? (float)(deg[m]+1) : 0.f;
    #pragma unroll
    for (int nt=0;nt<4;++nt){
      const int nb = n0 + wnq + nt*16 + quad*4;
      if (MODE == 0){
        bf16x4 o = { (bf16_t)(acc[mt][nt][0] + b4[nt].x),
                     (bf16_t)(acc[mt][nt][1] + b4[nt].y),
                     (bf16_t)(acc[mt][nt][2] + b4[nt].z),
                     (bf16_t)(acc[mt][nt][3] + b4[nt].w) };
        *(bf16x4*)((bf16_t*)C + (size_t)m*N + nb) = o;
      } else {
        const float4 xr = *(const float4*)(xres + (size_t)m*N + nb);
        float4 o;
        o.x = fmaxf(acc[mt][nt][0] + dg*b4[nt].x, 0.f) + xr.x;
        o.y = fmaxf(acc[mt][nt][1] + dg*b4[nt].y, 0.f) + xr.y;
        o.z = fmaxf(acc[mt][nt][2] + dg*b4[nt].z, 0.f) + xr.z;
        o.w = fmaxf(acc[mt][nt][3] + dg*b4[nt].w, 0.f) + xr.w;
        *(float4*)((float*)C + (size_t)m*N + nb) = o;
      }
    }
  }
}

// ---------- fused attention: score + online softmax + aggregate, one wave per node ----------
// P layout: [0,256) q; [256,768) kv-packed. BATCHED x4. off finalized on the fly via bsum.
__device__ __forceinline__ float score4(bf16x8 kvv, float4 qv, float4 b1v, float4 w2v){
  return fmaxf(qv.x+(float)kvv[0]+b1v.x, 0.f)*w2v.x
       + fmaxf(qv.y+(float)kvv[1]+b1v.y, 0.f)*w2v.y
       + fmaxf(qv.z+(float)kvv[2]+b1v.z, 0.f)*w2v.z
       + fmaxf(qv.w+(float)kvv[3]+b1v.w, 0.f)*w2v.w;
}
__device__ __forceinline__ float hredux(float p){
  #pragma unroll
  for (int o = 16; o >= 1; o >>= 1)
    p += __shfl_xor(p, o, 64);
  return p;
}
__global__ __launch_bounds__(256) void fused_attn_kernel(
    const bf16_t* __restrict__ P, const int* __restrict__ bj, const int* __restrict__ off,
    const int* __restrict__ bsum,
    const float* __restrict__ b1, const float* __restrict__ W2, const float* __restrict__ b2,
    bf16_t* __restrict__ aggb, int Nn)
{
  int i = blockIdx.x * (blockDim.x >> 6) + (threadIdx.x >> 6);
  if (i >= Nn) return;
  int lane = threadIdx.x & 63;
  int h = lane >> 5, g = lane & 31, d = g * 4;

  const float4 qv  = cvt4(*(const bf16x4*)(P + (size_t)i*768 + h*128 + d));
  const float4 b1v = *(const float4*)(b1 + d);
  const float4 w2v = *(const float4*)(W2 + d);
  const float b2v  = b2[0];
  const bf16_t* __restrict__ Pkv = P + 256 + h*256 + g*8;

  float m = -3.0e38f, s = 0.f;
  float4 acc = make_float4(0.f,0.f,0.f,0.f);
  const int s0 = off[i] + bsum[i>>10];
  const int s1 = (i+1 < Nn) ? off[i+1] + bsum[(i+1)>>10] : off[Nn];
  const int s1m1 = s1 - 1;

  for (int t = s0; t < s1; t += 4){
    const int cnt = s1 - t;                 // >= 1
    const int jA = bj[t];
    const int jB = bj[min(t+1, s1m1)];
    const int jC = bj[min(t+2, s1m1)];
    const int jD = bj[min(t+3, s1m1)];
    const bf16x8 kA = *(const bf16x8*)(Pkv + (size_t)jA*768);
    const bf16x8 kB = *(const bf16x8*)(Pkv + (size_t)jB*768);
    const bf16x8 kC = *(const bf16x8*)(Pkv + (size_t)jC*768);
    const bf16x8 kD = *(const bf16x8*)(Pkv + (size_t)jD*768);
    float pA = hredux(score4(kA, qv, b1v, w2v));
    float pB = hredux(score4(kB, qv, b1v, w2v));
    float pC = hredux(score4(kC, qv, b1v, w2v));
    float pD = hredux(score4(kD, qv, b1v, w2v));
    const float aA = pA + b2v;
    const float aB = (cnt > 1) ? pB + b2v : -3.0e38f;
    const float aC = (cnt > 2) ? pC + b2v : -3.0e38f;
    const float aD = (cnt > 3) ? pD + b2v : -3.0e38f;
    const float amax = fmaxf(fmaxf(aA, aB), fmaxf(aC, aD));
    const float mn = fmaxf(m, amax);
    const float sc = __expf(m - mn);
    const float eA = __expf(aA - mn);       // masked lanes -> exp(-inf) = 0
    const float eB = __expf(aB - mn);
    const float eC = __expf(aC - mn);
    const float eD = __expf(aD - mn);
    s = s*sc + ((eA + eB) + (eC + eD));
    acc.x = acc.x*sc + ((eA*(float)kA[4] + eB*(float)kB[4]) + (eC*(float)kC[4] + eD*(float)kD[4]));
    acc.y = acc.y*sc + ((eA*(float)kA[5] + eB*(float)kB[5]) + (eC*(float)kC[5] + eD*(float)kD[5]));
    acc.z = acc.z*sc + ((eA*(float)kA[6] + eB*(float)kB[6]) + (eC*(float)kC[6] + eD*(float)kD[6]));
    acc.w = acc.w*sc + ((eA*(float)kA[7] + eB*(float)kB[7]) + (eC*(float)kC[7] + eD*(float)kD[7]));
    m = mn;
  }
  float inv = 1.f / (s + 1e-16f);
  bf16x4 ob = { (bf16_t)(acc.x*inv), (bf16_t)(acc.y*inv), (bf16_t)(acc.z*inv), (bf16_t)(acc.w*inv) };
  *(bf16x4*)(aggb + (size_t)i*256 + h*128 + d) = ob;
}

// ---------- launch ----------
extern "C" void kernel_launch(void* const* d_in, const int* in_sizes, int n_in,
                              void* d_out, int out_size, void* d_ws, size_t ws_size,
                              hipStream_t stream)
{
  const float* x     = (const float*)d_in[0];
  const int*   ei    = (const int*)d_in[1];
  const float* Wkqv  = (const float*)d_in[2];
  const float* bkqv  = (const float*)d_in[3];
  const float* W1    = (const float*)d_in[4];
  const float* b1    = (const float*)d_in[5];
  const float* W2    = (const float*)d_in[6];
  const float* b2    = (const float*)d_in[7];
  const float* Wout  = (const float*)d_in[8];
  const float* bout  = (const float*)d_in[9];
  float* out = (float*)d_out;

  const int N  = in_sizes[0] / EMB;   // 50000
  const int E0 = in_sizes[1] / 2;     // 100000
  const int E  = 2*E0 + N;            // 250000

  // workspace layout (fp32-word offsets; all 16B-aligned)
  float* base = (float*)d_ws;
  bf16_t* WcombT = (bf16_t*)base;                       // 768*256 bf16
  float*  bcomb  = base + 98304;                        // 768 w
  bf16_t* WoutT  = (bf16_t*)(base + 98304 + 768);       // 256*256 bf16
  bf16_t* xb     = (bf16_t*)(base + 131840);            // N*256 bf16
  bf16_t* Pb     = (bf16_t*)(base + 131840 + 6400000);  // N*768 bf16
  bf16_t* aggb   = (bf16_t*)(Pb + (size_t)N*768);       // N*256 bf16
  int* deg       = (int*)(aggb + (size_t)N*256);        // N
  int* cursor    = deg + N;                             // N
  int* flag      = cursor + N;                          // 1 (unused)
  int* off       = flag + 1;                            // N+1
  int* bj        = off + (N+1);                         // E
  int* bsum      = bj + E;                              // <=1024 ints (own slot: attn
                                                        // reads it late, nothing clobbers)

  hipMemsetAsync(deg, 0, (size_t)2*N*sizeof(int), stream);  // deg + cursor

  // fused prep: cvt_x | prep_weights | prep_wout | deg
  const int n4 = N*EMB/4;
  const int G_CVT = (n4 + 255)/256;
  const int G_PW  = 3*257;
  const int G_WO  = 256;
  const int G_DEG = (2*E0 + 255)/256;
  prep_all_kernel<<<G_CVT+G_PW+G_WO+G_DEG,256,0,stream>>>(
      x, xb, n4, Wkqv, bkqv, W1, WcombT, bcomb, Wout, WoutT, ei, deg, E0, N,
      G_CVT, G_PW, G_WO);

  const int nb = (N + 1023)/1024;
  scan1_kernel<<<nb,1024,0,stream>>>(deg, off, bsum, N);
  scan2_kernel<<<1,1024,0,stream>>>(bsum, off, nb, N);
  scatter_kernel<<<(E+255)/256,256,0,stream>>>(ei, off, bsum, cursor, bj, E0, N);

  // gemm<0>: 256x256 tiles, BK=64 (m-strips padded to mult of 8 for XCD swizzle)
  const int nm256 = (((N+255)/256) + 7) & ~7;   // 200
  mfma_gemm256T<0, bf16_t><<<nm256*3,1024,0,stream>>>(
      xb, WcombT, bcomb, Pb, N, 768, nullptr, nullptr);
  fused_attn_kernel<<<(N+3)/4,256,0,stream>>>(Pb, bj, off, bsum, b1, W2, b2, aggb, N);
  // gemm<1>: 256x256 tiles, BK=64, single n-strip -> 200 blocks
  mfma_gemm256T<1, float><<<nm256,1024,0,stream>>>(
      aggb, WoutT, bout, out, N, 256, deg, x);
}